// Round 8
// baseline (760.400 us; speedup 1.0000x reference)
//
#include <hip/hip_runtime.h>
#include <hip/hip_bf16.h>
#include <hip/hip_cooperative_groups.h>

namespace cg = cooperative_groups;

// GCN 2-layer: out = A' relu(A' (xW1) + b1) W2 + b2, A' = D^-1/2 (A+I) D^-1/2
// R8: ONE persistent cooperative kernel (grid.sync between phases) replaces 9
// dispatches (~120us of inter-dispatch gaps). Phases: P0 detect+zero+Wprep,
// P1 binA, P2 binB(+bucket scan), P3 gemm1, P4 gather1, P5 gemm2, P6 gather2.
// GEMM = R6 single-buffer MFMA bf16x3 (R7 dbuf was neutral: reverted).
// Assumes N <= 65535 (harness: N=50000) so (d,s) packs into 32 bits.

typedef __attribute__((ext_vector_type(8))) short short8;
typedef __attribute__((ext_vector_type(4))) float f32x4;

#define BSHIFT 9
#define BSIZE 512
constexpr int NBMAX = 128;
constexpr int CAP = 32768;   // pair slots per coarse bucket (mean ~16.3K)
constexpr int CHUNK = 4096;  // edges per binA chunk

__device__ __forceinline__ unsigned short bf16_bits(float f) {
  __hip_bfloat16 h = __float2bfloat16(f);
  return *(unsigned short*)&h;
}
__device__ __forceinline__ float bf16_f(unsigned short u) {
  __hip_bfloat16 h = *(__hip_bfloat16*)&u;
  return __bfloat162float(h);
}
__device__ __forceinline__ void gload_lds16(const void* g, void* l) {
  __builtin_amdgcn_global_load_lds(
      (const __attribute__((address_space(1))) unsigned*)g,
      (__attribute__((address_space(3))) unsigned*)l, 16, 0, 0);
}
__device__ __forceinline__ int edge_at(const void* p, long long i, int is64) {
  return is64 ? (int)((const long long*)p)[i] : ((const int*)p)[i];
}

struct GcnParams {
  const float* x; const void* ei;
  const float* W1; const float* b1; const float* W2; const float* b2;
  float* out;
  int N, E, NB, nchunks;
  int* flag; int* ccur; int* rowptr; float* dinv; int* elist;
  unsigned* pairs;
  unsigned short *W1h, *W1l, *W2h, *W2l;
  unsigned short* Hs;  // bf16 messages (also reused as Hs2)
  float* h2;
};

// Single-buffer MFMA GEMM tile (R6): Hs(bf16) = (X @ W) * dinv, bf16x3 split.
// Wave tile WM x 64, wave grid WY x WX; BM = WM*WY, BN = 64*WX = NOUT.
// LDS rows KC=32 bf16 = 64 B unpadded (global_load_lds order matches exactly).
template <int K, int NOUT, int WM, int WY, int WX>
__device__ __forceinline__ void gemm_tile(
    const float* __restrict__ X, const unsigned short* __restrict__ Whi,
    const unsigned short* __restrict__ Wlo, const float* __restrict__ dinv,
    unsigned short* __restrict__ Hs, int M, int tile, char* smem) {
  constexpr int BM = WM * WY;
  constexpr int BN = 64 * WX;
  constexpr int KC = 32;
  constexpr int I = WM / 16;
  static_assert(WY * WX == 4, "4 waves");
  static_assert((BM + BM + BN + BN) * KC * 2 <= 24576, "fits smem");
  unsigned short* Ah = (unsigned short*)smem;  // [BM][KC]
  unsigned short* Al = Ah + BM * KC;
  unsigned short* Bh = Al + BM * KC;           // [BN][KC]
  unsigned short* Bl = Bh + BN * KC;
  const int tid = threadIdx.x;
  const int lane = tid & 63, wv = tid >> 6;
  const int wy = wv / WX, wx = wv % WX;
  const int fm = lane & 15;
  const int fq = lane >> 4;
  const int base = tile * BM;

  f32x4 acc[I][4];
#pragma unroll
  for (int i = 0; i < I; ++i)
#pragma unroll
    for (int j = 0; j < 4; ++j) acc[i][j] = (f32x4){0.f, 0.f, 0.f, 0.f};

  for (int k0 = 0; k0 < K; k0 += KC) {
    __syncthreads();
    // stage + split A: BM x 32 fp32 -> bf16 hi/lo
#pragma unroll
    for (int it = 0; it < BM / 32; ++it) {
      int chunk = tid + it * 256;
      int r = chunk >> 3, c = chunk & 7;
      float4 v = make_float4(0.f, 0.f, 0.f, 0.f);
      if (base + r < M) v = *(const float4*)&X[(long long)(base + r) * K + k0 + c * 4];
      ushort4 hv, lv;
      hv.x = bf16_bits(v.x); lv.x = bf16_bits(v.x - bf16_f(hv.x));
      hv.y = bf16_bits(v.y); lv.y = bf16_bits(v.y - bf16_f(hv.y));
      hv.z = bf16_bits(v.z); lv.z = bf16_bits(v.z - bf16_f(hv.z));
      hv.w = bf16_bits(v.w); lv.w = bf16_bits(v.w - bf16_f(hv.w));
      *(ushort4*)&Ah[r * KC + c * 4] = hv;
      *(ushort4*)&Al[r * KC + c * 4] = lv;
    }
    // stage B via global_load_lds: 16 B chunks, wave-uniform base + lane*16
#pragma unroll
    for (int it = 0; it < (BN * 4) / 256; ++it) {
      int cb = it * 256 + wv * 64;
      int chunk = cb + lane;
      int n = chunk >> 2, cc = chunk & 3;
      const long long go = (long long)n * K + k0 + cc * 8;
      gload_lds16(&Whi[go], Bh + (size_t)cb * 8);
      gload_lds16(&Wlo[go], Bl + (size_t)cb * 8);
    }
    __syncthreads();
    short8 ah[I], al[I], bh[4], bl[4];
#pragma unroll
    for (int i = 0; i < I; ++i) {
      ah[i] = *(short8*)&Ah[(wy * WM + i * 16 + fm) * KC + fq * 8];
      al[i] = *(short8*)&Al[(wy * WM + i * 16 + fm) * KC + fq * 8];
    }
#pragma unroll
    for (int j = 0; j < 4; ++j) {
      bh[j] = *(short8*)&Bh[(wx * 64 + j * 16 + fm) * KC + fq * 8];
      bl[j] = *(short8*)&Bl[(wx * 64 + j * 16 + fm) * KC + fq * 8];
    }
#pragma unroll
    for (int i = 0; i < I; ++i)
#pragma unroll
      for (int j = 0; j < 4; ++j) {
        acc[i][j] = __builtin_amdgcn_mfma_f32_16x16x32_bf16(ah[i], bh[j], acc[i][j], 0, 0, 0);
        acc[i][j] = __builtin_amdgcn_mfma_f32_16x16x32_bf16(ah[i], bl[j], acc[i][j], 0, 0, 0);
        acc[i][j] = __builtin_amdgcn_mfma_f32_16x16x32_bf16(al[i], bh[j], acc[i][j], 0, 0, 0);
      }
  }
  // epilogue: C/D layout col=lane&15, row=fq*4+reg
#pragma unroll
  for (int i = 0; i < I; ++i) {
#pragma unroll
    for (int reg = 0; reg < 4; ++reg) {
      int row = base + wy * WM + i * 16 + fq * 4 + reg;
      if (row < M) {
        float dv = dinv[row];
#pragma unroll
        for (int j = 0; j < 4; ++j)
          Hs[(long long)row * NOUT + wx * 64 + j * 16 + fm] =
              bf16_bits(acc[i][j][reg] * dv);
      }
    }
  }
}

// Accumulate 8 bf16 (one uint4) into 8 fp32.
__device__ __forceinline__ void acc8(float* a, uint4 u) {
  const unsigned* p = (const unsigned*)&u;
#pragma unroll
  for (int q = 0; q < 4; ++q) {
    unsigned w = p[q];
    a[2 * q]     += __uint_as_float(w << 16);
    a[2 * q + 1] += __uint_as_float(w & 0xFFFF0000u);
  }
}

// One group of the gather-aggregate:
// OUT[d] = act(dinv[d] * (sum_{s in in(d)} Hs[s] + Hs[d]) + bias)
template <int C, bool RELU>
__device__ __forceinline__ void gather_grp(
    const int* __restrict__ rowptr, const int* __restrict__ elist,
    const float* __restrict__ dinv, const unsigned short* __restrict__ Hs,
    const float* __restrict__ bias, float* __restrict__ OUT, int N, int g) {
  constexpr int TPN = C / 8;      // threads per node (8 bf16 = 16 B each)
  constexpr int NPB = 256 / TPN;  // nodes per group
  const int node = g * NPB + (int)threadIdx.x / TPN;
  const int lane = (int)threadIdx.x % TPN;
  if (node >= N) return;
  const int col = lane * 8;
  const int beg = rowptr[node];
  const int end = rowptr[node + 1];
  float a0[8] = {0, 0, 0, 0, 0, 0, 0, 0};
  float a1[8] = {0, 0, 0, 0, 0, 0, 0, 0};
  acc8(a0, *(const uint4*)&Hs[(long long)node * C + col]);  // self-loop
  int e = beg;
  for (; e + 3 < end; e += 4) {
    int s0 = elist[e], s1 = elist[e + 1], s2 = elist[e + 2], s3 = elist[e + 3];
    uint4 v0 = *(const uint4*)&Hs[(long long)s0 * C + col];
    uint4 v1 = *(const uint4*)&Hs[(long long)s1 * C + col];
    uint4 v2 = *(const uint4*)&Hs[(long long)s2 * C + col];
    uint4 v3 = *(const uint4*)&Hs[(long long)s3 * C + col];
    acc8(a0, v0); acc8(a1, v1); acc8(a0, v2); acc8(a1, v3);
  }
  for (; e < end; ++e) {
    uint4 v0 = *(const uint4*)&Hs[(long long)elist[e] * C + col];
    acc8(a0, v0);
  }
  const float dv = dinv[node];
  float o[8];
#pragma unroll
  for (int i = 0; i < 8; ++i) {
    o[i] = (a0[i] + a1[i]) * dv + bias[col + i];
    if (RELU) o[i] = fmaxf(o[i], 0.f);
  }
  *(float4*)&OUT[(long long)node * C + col] = make_float4(o[0], o[1], o[2], o[3]);
  *(float4*)&OUT[(long long)node * C + col + 4] = make_float4(o[4], o[5], o[6], o[7]);
}

__global__ __launch_bounds__(256, 4) void k_fused(GcnParams p) {
  cg::grid_group grid = cg::this_grid();
  __shared__ __align__(16) char smem[24576];
  const int tid = threadIdx.x;
  const int bid = blockIdx.x;
  const int nb = gridDim.x;

  // ---- P0: block 0 detects int64 storage + zeroes ccur; all blocks Wprep ----
  if (bid == 0) {
    int* s = (int*)smem;
    if (tid == 0) s[0] = 0;
    __syncthreads();
    int nz = 0;
    for (int i = 1 + 2 * tid; i < 4096; i += 512)
      nz |= (((const int*)p.ei)[i] != 0);
    if (nz) s[0] = 1;
    if (tid < NBMAX) p.ccur[tid] = 0;
    __syncthreads();
    if (tid == 0) *p.flag = (s[0] == 0) ? 1 : 0;
  }
  {  // weight prep: W[K,N] fp32 -> [N,K] bf16 hi/lo (288 jobs of 256 elems)
    constexpr int JT = (512 * 128 + 128 * 64) / 256;
    for (int j = bid; j < JT; j += nb) {
      int o = j * 256 + tid;
      const float* W; unsigned short *Wh, *Wl; int K, Nn;
      if (o < 512 * 128) { W = p.W1; Wh = p.W1h; Wl = p.W1l; K = 512; Nn = 128; }
      else { o -= 512 * 128; W = p.W2; Wh = p.W2h; Wl = p.W2l; K = 128; Nn = 64; }
      int n = o / K, k = o % K;
      float w = W[(long long)k * Nn + n];
      unsigned short hb = bf16_bits(w);
      Wh[o] = hb;
      Wl[o] = bf16_bits(w - bf16_f(hb));
    }
  }
  grid.sync();

  // ---- P1: coarse binning (LDS counting-sort per 4096-edge chunk) ----
  {
    const int is64 = *p.flag;
    int* cnt = (int*)smem;            // 128
    int* scn = cnt + NBMAX;           // 129
    int* cur = scn + NBMAX + 4;       // 128
    int* gbase = cur + NBMAX;         // 128
    unsigned* out = (unsigned*)(smem + 4096);  // 4096 u32 = 16 KB
    for (int c = bid; c < p.nchunks; c += nb) {
      const int cs = c * CHUNK;
      const int n = min(CHUNK, p.E - cs);
      for (int b = tid; b < NBMAX; b += 256) cnt[b] = 0;
      __syncthreads();
      unsigned pk[CHUNK / 256];
#pragma unroll
      for (int it = 0; it < CHUNK / 256; ++it) {
        int i = cs + it * 256 + tid;
        unsigned pe = 0xFFFFFFFFu;
        if (i < p.E) {
          int s = edge_at(p.ei, i, is64);
          int d = edge_at(p.ei, (long long)p.E + i, is64);
          pe = ((unsigned)d << 16) | (unsigned)s;
          atomicAdd(&cnt[d >> BSHIFT], 1);
        }
        pk[it] = pe;
      }
      __syncthreads();
      if (tid < p.NB) scn[tid + 1] = cnt[tid];
      if (tid == 0) scn[0] = 0;
      __syncthreads();
      for (int off = 1; off < p.NB; off <<= 1) {
        int t = 0;
        if (tid < p.NB && tid + 1 > off) t = scn[tid + 1 - off];
        __syncthreads();
        if (tid < p.NB && tid + 1 > off) scn[tid + 1] += t;
        __syncthreads();
      }
      if (tid < p.NB) {
        cur[tid] = scn[tid];
        gbase[tid] = (cnt[tid] > 0)
            ? (tid * CAP + atomicAdd(&p.ccur[tid], cnt[tid])) : 0;
      }
      __syncthreads();
#pragma unroll
      for (int it = 0; it < CHUNK / 256; ++it) {
        unsigned pe = pk[it];
        if (pe != 0xFFFFFFFFu) {
          int b = (int)(pe >> (16 + BSHIFT));
          int pos = atomicAdd(&cur[b], 1);
          out[pos] = pe;
        }
      }
      __syncthreads();
      for (int p2 = tid; p2 < n; p2 += 256) {
        unsigned v = out[p2];
        int b = (int)(v >> (16 + BSHIFT));
        p.pairs[gbase[b] + (p2 - scn[b])] = v;
      }
    }
  }
  grid.sync();

  // ---- P2: per-bucket histogram+scan -> rowptr/dinv/elist ----
  if (bid == 0 && tid == 0) p.rowptr[p.N] = p.E;
  if (bid < p.NB) {
    int* scn2 = (int*)smem;                  // 128
    int* hist = (int*)(smem + 1024);         // 512
    int* loc  = (int*)(smem + 1024 + 2048);  // 512
    if (tid < NBMAX) scn2[tid] = (tid < p.NB) ? p.ccur[tid] : 0;
    __syncthreads();
    for (int off = 1; off < NBMAX; off <<= 1) {
      int t = (tid < NBMAX && tid >= off) ? scn2[tid - off] : 0;
      __syncthreads();
      if (tid < NBMAX) scn2[tid] += t;
      __syncthreads();
    }
    const int cntb = p.ccur[bid];
    const int base = scn2[bid] - cntb;  // exclusive prefix
    const int nbeg = bid * CAP;
    const int j0 = tid, j1 = tid + 256;
    hist[j0] = 0; hist[j1] = 0;
    __syncthreads();
    for (int i = tid; i < cntb; i += 256) {
      unsigned v = p.pairs[nbeg + i];
      atomicAdd(&hist[(v >> 16) & (BSIZE - 1)], 1);
    }
    __syncthreads();
    loc[j0] = hist[j0]; loc[j1] = hist[j1];
    __syncthreads();
    for (int off = 1; off < BSIZE; off <<= 1) {
      int v0 = (j0 >= off) ? loc[j0 - off] : 0;
      int v1 = (j1 >= off) ? loc[j1 - off] : 0;
      __syncthreads();
      loc[j0] += v0; loc[j1] += v1;
      __syncthreads();
    }
    int c0 = base + loc[j0] - hist[j0];
    int c1 = base + loc[j1] - hist[j1];
    int gd0 = bid * BSIZE + j0, gd1 = bid * BSIZE + j1;
    if (gd0 < p.N) { p.rowptr[gd0] = c0; p.dinv[gd0] = rsqrtf((float)(hist[j0] + 1)); }
    if (gd1 < p.N) { p.rowptr[gd1] = c1; p.dinv[gd1] = rsqrtf((float)(hist[j1] + 1)); }
    __syncthreads();
    hist[j0] = c0; hist[j1] = c1;  // reuse as cursors
    __syncthreads();
    for (int i = tid; i < cntb; i += 256) {
      unsigned v = p.pairs[nbeg + i];
      int pos = atomicAdd(&hist[(v >> 16) & (BSIZE - 1)], 1);
      p.elist[pos] = (int)(v & 0xFFFFu);
    }
  }
  grid.sync();

  // ---- P3: layer-1 GEMM (BM=64, BN=128 -> 782 tiles) ----
  {
    const int nt = (p.N + 63) / 64;
    for (int t = bid; t < nt; t += nb)
      gemm_tile<512, 128, 32, 2, 2>(p.x, p.W1h, p.W1l, p.dinv, p.Hs, p.N, t, smem);
  }
  grid.sync();

  // ---- P4: gather layer 1 (+bias+relu) -> h2 fp32 ----
  {
    const int ng = (p.N + 15) / 16;
    for (int g = bid; g < ng; g += nb)
      gather_grp<128, true>(p.rowptr, p.elist, p.dinv, p.Hs, p.b1, p.h2, p.N, g);
  }
  grid.sync();

  // ---- P5: layer-2 GEMM (BM=128, BN=64 -> 391 tiles), Hs reused ----
  {
    const int nt = (p.N + 127) / 128;
    for (int t = bid; t < nt; t += nb)
      gemm_tile<128, 64, 32, 4, 1>(p.h2, p.W2h, p.W2l, p.dinv, p.Hs, p.N, t, smem);
  }
  grid.sync();

  // ---- P6: gather layer 2 (+bias) -> out fp32 ----
  {
    const int ng = (p.N + 31) / 32;
    for (int g = bid; g < ng; g += nb)
      gather_grp<64, false>(p.rowptr, p.elist, p.dinv, p.Hs, p.b2, p.out, p.N, g);
  }
}

extern "C" void kernel_launch(void* const* d_in, const int* in_sizes, int n_in,
                              void* d_out, int out_size, void* d_ws, size_t ws_size,
                              hipStream_t stream) {
  const int N = in_sizes[0] / 512;  // 50000
  const int E = in_sizes[1] / 2;    // 1600000

  char* ws = (char*)d_ws;
  size_t off = 0;
  auto take = [&](size_t bytes) {
    void* ptr = ws + off;
    off = (off + bytes + 255) & ~(size_t)255;
    return ptr;
  };
  GcnParams p;
  p.x  = (const float*)d_in[0];
  p.ei = d_in[1];
  p.W1 = (const float*)d_in[2];
  p.b1 = (const float*)d_in[3];
  p.W2 = (const float*)d_in[4];
  p.b2 = (const float*)d_in[5];
  p.out = (float*)d_out;
  p.N = N;
  p.E = E;
  p.NB = (N + BSIZE - 1) >> BSHIFT;       // 98
  p.nchunks = (E + CHUNK - 1) / CHUNK;    // 391
  p.dinv   = (float*)take((size_t)N * 4);
  p.flag   = (int*)take(4);
  p.rowptr = (int*)take((size_t)(N + 1) * 4);
  p.ccur   = (int*)take((size_t)NBMAX * 4);
  p.elist  = (int*)take((size_t)E * 4);
  p.W1h = (unsigned short*)take((size_t)512 * 128 * 2);
  p.W1l = (unsigned short*)take((size_t)512 * 128 * 2);
  p.W2h = (unsigned short*)take((size_t)128 * 64 * 2);
  p.W2l = (unsigned short*)take((size_t)128 * 64 * 2);
  p.Hs  = (unsigned short*)take((size_t)N * 128 * 2);  // bf16 messages
  p.h2  = (float*)take((size_t)N * 128 * 4);
  p.pairs = (unsigned*)p.h2;  // alias: pairs (12.85 MB) dead before h2 written

  int maxb = 4;
  hipOccupancyMaxActiveBlocksPerMultiprocessor(&maxb, k_fused, 256, 0);
  if (maxb < 1) maxb = 1;
  long long g = (long long)maxb * 256;  // 256 CUs on MI355X
  if (g > 1536) g = 1536;
  if (g < 256) g = 256;
  void* args[] = {(void*)&p};
  hipLaunchCooperativeKernel((const void*)k_fused, dim3((unsigned)g), dim3(256),
                             args, 0, stream);
}

// Round 9
// 340.563 us; speedup vs baseline: 2.2328x; 2.2328x over previous
//
#include <hip/hip_runtime.h>
#include <hip/hip_bf16.h>

// GCN 2-layer: out = A' relu(A' (xW1) + b1) W2 + b2, A' = D^-1/2 (A+I) D^-1/2
// R9: back to multi-kernel (R8 cooperative grid.sync was 2x regression).
// Dispatch-count reduction: detect inlined into binA blocks, weight-prep as
// extra binA blocks, bucket-scan inlined into binB, ccur zeroed by memset.
// elist stored ushort (N<65536). R6 GEMM (single-buffer MFMA bf16x3).
// 6 kernels + 1 memset vs R6's 9 kernels.

typedef __attribute__((ext_vector_type(8))) short short8;
typedef __attribute__((ext_vector_type(4))) float f32x4;

#define BSHIFT 9
#define BSIZE 512
constexpr int NBMAX = 128;
constexpr int CAP = 32768;   // pair slots per coarse bucket (mean ~16.3K)
constexpr int CHUNK = 4096;  // edges per binA block

__device__ __forceinline__ unsigned short bf16_bits(float f) {
  __hip_bfloat16 h = __float2bfloat16(f);
  return *(unsigned short*)&h;
}
__device__ __forceinline__ float bf16_f(unsigned short u) {
  __hip_bfloat16 h = *(__hip_bfloat16*)&u;
  return __bfloat162float(h);
}
__device__ __forceinline__ void gload_lds16(const void* g, void* l) {
  __builtin_amdgcn_global_load_lds(
      (const __attribute__((address_space(1))) unsigned*)g,
      (__attribute__((address_space(3))) unsigned*)l, 16, 0, 0);
}
__device__ __forceinline__ int edge_at(const void* p, long long i, int is64) {
  return is64 ? (int)((const long long*)p)[i] : ((const int*)p)[i];
}

// Coarse binning (blocks < nchunks): LDS counting-sort of a 4096-edge chunk by
// bucket = d>>9, flush contiguous runs into per-bucket pair regions.
// Blocks >= nchunks: weight prep W[K,N] fp32 -> [N,K] bf16 hi/lo (288 jobs).
__global__ __launch_bounds__(256) void k_binA(
    const void* __restrict__ eidx, int* __restrict__ ccur,
    unsigned* __restrict__ pairs,
    const float* __restrict__ W1, unsigned short* __restrict__ W1h,
    unsigned short* __restrict__ W1l,
    const float* __restrict__ W2, unsigned short* __restrict__ W2h,
    unsigned short* __restrict__ W2l, int E, int NB, int nchunks) {
  const int tid = threadIdx.x;
  if ((int)blockIdx.x >= nchunks) {  // ---- weight prep ----
    int o = ((int)blockIdx.x - nchunks) * 256 + tid;
    const float* W; unsigned short *Wh, *Wl; int K, Nn;
    if (o < 512 * 128) { W = W1; Wh = W1h; Wl = W1l; K = 512; Nn = 128; }
    else { o -= 512 * 128; if (o >= 128 * 64) return;
           W = W2; Wh = W2h; Wl = W2l; K = 128; Nn = 64; }
    int n = o / K, k = o % K;
    float w = W[(long long)k * Nn + n];
    unsigned short hb = bf16_bits(w);
    Wh[o] = hb;
    Wl[o] = bf16_bits(w - bf16_f(hb));
    return;
  }
  __shared__ int s_nz;
  __shared__ int cnt[NBMAX];
  __shared__ int scn[NBMAX + 1];
  __shared__ int cur[NBMAX];
  __shared__ int gbase[NBMAX];
  __shared__ unsigned out[CHUNK];
  // inline int64-storage detection (odd 32-bit words of 16 KB sample all zero)
  if (tid == 0) s_nz = 0;
  for (int b = tid; b < NBMAX; b += 256) cnt[b] = 0;
  __syncthreads();
  {
    int nz = 0;
    for (int i = 1 + 2 * tid; i < 4096; i += 512)
      nz |= (((const int*)eidx)[i] != 0);
    if (nz) atomicOr(&s_nz, 1);
  }
  __syncthreads();
  const int is64 = (s_nz == 0) ? 1 : 0;
  const int cs = blockIdx.x * CHUNK;
  const int n = min(CHUNK, E - cs);
  unsigned pk[CHUNK / 256];
#pragma unroll
  for (int it = 0; it < CHUNK / 256; ++it) {
    int i = cs + it * 256 + tid;
    unsigned p = 0xFFFFFFFFu;
    if (i < E) {
      int s = edge_at(eidx, i, is64);
      int d = edge_at(eidx, (long long)E + i, is64);
      p = ((unsigned)d << 16) | (unsigned)s;
      atomicAdd(&cnt[d >> BSHIFT], 1);
    }
    pk[it] = p;
  }
  __syncthreads();
  if (tid < NB) scn[tid + 1] = cnt[tid];
  if (tid == 0) scn[0] = 0;
  __syncthreads();
  for (int off = 1; off < NB; off <<= 1) {
    int t = 0;
    if (tid < NB && tid + 1 > off) t = scn[tid + 1 - off];
    __syncthreads();
    if (tid < NB && tid + 1 > off) scn[tid + 1] += t;
    __syncthreads();
  }
  if (tid < NB) {
    cur[tid] = scn[tid];
    gbase[tid] = (cnt[tid] > 0)
        ? (tid * CAP + atomicAdd(&ccur[tid], cnt[tid])) : 0;
  }
  __syncthreads();
#pragma unroll
  for (int it = 0; it < CHUNK / 256; ++it) {
    unsigned p = pk[it];
    if (p != 0xFFFFFFFFu) {
      int b = (int)(p >> (16 + BSHIFT));
      int pos = atomicAdd(&cur[b], 1);
      out[pos] = p;
    }
  }
  __syncthreads();
  for (int p2 = tid; p2 < n; p2 += 256) {
    unsigned v = out[p2];
    int b = (int)(v >> (16 + BSHIFT));
    pairs[gbase[b] + (p2 - scn[b])] = v;  // contiguous run per bucket
  }
}

// Per-bucket: scan of bucket counts (inlined) + LDS histogram + scan ->
// rowptr/dinv; place src into dense elist window via LDS cursors.
__global__ __launch_bounds__(256) void k_binB(
    const unsigned* __restrict__ pairs, const int* __restrict__ ccur,
    int* __restrict__ rowptr, float* __restrict__ dinv,
    unsigned short* __restrict__ elist, int N, int NB, int E) {
  __shared__ int scn2[NBMAX];
  __shared__ int hist[BSIZE];
  __shared__ int loc[BSIZE];
  const int b = blockIdx.x;
  const int tid = threadIdx.x;
  if (b == 0 && tid == 0) rowptr[N] = E;
  // inclusive scan of ccur over NB buckets (tiny, redone per block)
  if (tid < NBMAX) scn2[tid] = (tid < NB) ? ccur[tid] : 0;
  __syncthreads();
  for (int off = 1; off < NBMAX; off <<= 1) {
    int t = (tid < NBMAX && tid >= off) ? scn2[tid - off] : 0;
    __syncthreads();
    if (tid < NBMAX) scn2[tid] += t;
    __syncthreads();
  }
  const int cntb = ccur[b];
  const int base = scn2[b] - cntb;  // exclusive prefix
  const int nbeg = b * CAP;
  const int j0 = tid, j1 = tid + 256;
  hist[j0] = 0; hist[j1] = 0;
  __syncthreads();
  for (int i = tid; i < cntb; i += 256) {
    unsigned v = pairs[nbeg + i];
    atomicAdd(&hist[(v >> 16) & (BSIZE - 1)], 1);
  }
  __syncthreads();
  loc[j0] = hist[j0]; loc[j1] = hist[j1];
  __syncthreads();
  for (int off = 1; off < BSIZE; off <<= 1) {
    int v0 = (j0 >= off) ? loc[j0 - off] : 0;
    int v1 = (j1 >= off) ? loc[j1 - off] : 0;
    __syncthreads();
    loc[j0] += v0; loc[j1] += v1;
    __syncthreads();
  }
  int c0 = base + loc[j0] - hist[j0];
  int c1 = base + loc[j1] - hist[j1];
  int gd0 = b * BSIZE + j0, gd1 = b * BSIZE + j1;
  if (gd0 < N) { rowptr[gd0] = c0; dinv[gd0] = rsqrtf((float)(hist[j0] + 1)); }
  if (gd1 < N) { rowptr[gd1] = c1; dinv[gd1] = rsqrtf((float)(hist[j1] + 1)); }
  __syncthreads();
  hist[j0] = c0; hist[j1] = c1;  // reuse as cursors
  __syncthreads();
  for (int i = tid; i < cntb; i += 256) {
    unsigned v = pairs[nbeg + i];
    int pos = atomicAdd(&hist[(v >> 16) & (BSIZE - 1)], 1);
    elist[pos] = (unsigned short)(v & 0xFFFFu);
  }
}

// MFMA GEMM (R6): Hs(bf16) = (X[M,K] @ W[K,NOUT]) * dinv[row], bf16x3 split.
// Wave tile WM x 64; wave grid WY x WX; BM = WM*WY, BN = 64*WX = NOUT.
// LDS rows KC=32 bf16 = 64 B unpadded (global_load_lds order matches exactly).
template <int K, int NOUT, int WM, int WY, int WX>
__global__ __launch_bounds__(256) void k_gemm_mfma(
    const float* __restrict__ X, const unsigned short* __restrict__ Whi,
    const unsigned short* __restrict__ Wlo, const float* __restrict__ dinv,
    unsigned short* __restrict__ Hs, int M) {
  constexpr int BM = WM * WY;
  constexpr int BN = 64 * WX;
  constexpr int KC = 32;
  constexpr int I = WM / 16;
  static_assert(WY * WX == 4, "4 waves");
  static_assert(BN == NOUT, "block covers full N");
  __shared__ unsigned short Ah[BM][KC], Al[BM][KC];
  __shared__ unsigned short Bh[BN][KC], Bl[BN][KC];
  const int tid = threadIdx.x;
  const int lane = tid & 63, wv = tid >> 6;
  const int wy = wv / WX, wx = wv % WX;
  const int fm = lane & 15;
  const int fq = lane >> 4;
  const int base = blockIdx.x * BM;

  f32x4 acc[I][4];
#pragma unroll
  for (int i = 0; i < I; ++i)
#pragma unroll
    for (int j = 0; j < 4; ++j) acc[i][j] = (f32x4){0.f, 0.f, 0.f, 0.f};

  for (int k0 = 0; k0 < K; k0 += KC) {
    __syncthreads();
#pragma unroll
    for (int it = 0; it < BM / 32; ++it) {
      int chunk = tid + it * 256;
      int r = chunk >> 3, c = chunk & 7;
      float4 v = make_float4(0.f, 0.f, 0.f, 0.f);
      if (base + r < M) v = *(const float4*)&X[(long long)(base + r) * K + k0 + c * 4];
      ushort4 hv, lv;
      hv.x = bf16_bits(v.x); lv.x = bf16_bits(v.x - bf16_f(hv.x));
      hv.y = bf16_bits(v.y); lv.y = bf16_bits(v.y - bf16_f(hv.y));
      hv.z = bf16_bits(v.z); lv.z = bf16_bits(v.z - bf16_f(hv.z));
      hv.w = bf16_bits(v.w); lv.w = bf16_bits(v.w - bf16_f(hv.w));
      *(ushort4*)&Ah[r][c * 4] = hv;
      *(ushort4*)&Al[r][c * 4] = lv;
    }
#pragma unroll
    for (int it = 0; it < (BN * 4) / 256; ++it) {
      int cb = it * 256 + wv * 64;  // wave-uniform chunk base
      int chunk = cb + lane;
      int n = chunk >> 2, cc = chunk & 3;
      const long long go = (long long)n * K + k0 + cc * 8;
      gload_lds16(&Whi[go], (unsigned short*)Bh + (size_t)cb * 8);
      gload_lds16(&Wlo[go], (unsigned short*)Bl + (size_t)cb * 8);
    }
    __syncthreads();
    short8 ah[I], al[I], bh[4], bl[4];
#pragma unroll
    for (int i = 0; i < I; ++i) {
      ah[i] = *(short8*)&Ah[wy * WM + i * 16 + fm][fq * 8];
      al[i] = *(short8*)&Al[wy * WM + i * 16 + fm][fq * 8];
    }
#pragma unroll
    for (int j = 0; j < 4; ++j) {
      bh[j] = *(short8*)&Bh[wx * 64 + j * 16 + fm][fq * 8];
      bl[j] = *(short8*)&Bl[wx * 64 + j * 16 + fm][fq * 8];
    }
#pragma unroll
    for (int i = 0; i < I; ++i)
#pragma unroll
      for (int j = 0; j < 4; ++j) {
        acc[i][j] = __builtin_amdgcn_mfma_f32_16x16x32_bf16(ah[i], bh[j], acc[i][j], 0, 0, 0);
        acc[i][j] = __builtin_amdgcn_mfma_f32_16x16x32_bf16(ah[i], bl[j], acc[i][j], 0, 0, 0);
        acc[i][j] = __builtin_amdgcn_mfma_f32_16x16x32_bf16(al[i], bh[j], acc[i][j], 0, 0, 0);
      }
  }
  // epilogue: C/D layout col=lane&15, row=fq*4+reg
#pragma unroll
  for (int i = 0; i < I; ++i) {
#pragma unroll
    for (int reg = 0; reg < 4; ++reg) {
      int row = base + wy * WM + i * 16 + fq * 4 + reg;
      if (row < M) {
        float dv = dinv[row];
#pragma unroll
        for (int j = 0; j < 4; ++j)
          Hs[(long long)row * NOUT + wx * 64 + j * 16 + fm] =
              bf16_bits(acc[i][j][reg] * dv);
      }
    }
  }
}

// Accumulate 8 bf16 (one uint4) into 8 fp32.
__device__ __forceinline__ void acc8(float* a, uint4 u) {
  const unsigned* p = (const unsigned*)&u;
#pragma unroll
  for (int q = 0; q < 4; ++q) {
    unsigned w = p[q];
    a[2 * q]     += __uint_as_float(w << 16);
    a[2 * q + 1] += __uint_as_float(w & 0xFFFF0000u);
  }
}

// Gather-aggregate from bf16 Hs:
// OUT[d] = act(dinv[d] * (sum_{s in in(d)} Hs[s] + Hs[d]) + bias), fp32 out.
template <int C, bool RELU>
__global__ __launch_bounds__(256) void k_gather(
    const int* __restrict__ rowptr, const unsigned short* __restrict__ elist,
    const float* __restrict__ dinv, const unsigned short* __restrict__ Hs,
    const float* __restrict__ bias, float* __restrict__ OUT, int N) {
  constexpr int TPN = C / 8;      // threads per node (8 bf16 = 16 B each)
  constexpr int NPB = 256 / TPN;  // nodes per block
  const int node = blockIdx.x * NPB + (int)threadIdx.x / TPN;
  const int lane = (int)threadIdx.x % TPN;
  if (node >= N) return;
  const int col = lane * 8;
  const int beg = rowptr[node];
  const int end = rowptr[node + 1];
  float a0[8] = {0, 0, 0, 0, 0, 0, 0, 0};
  float a1[8] = {0, 0, 0, 0, 0, 0, 0, 0};
  acc8(a0, *(const uint4*)&Hs[(long long)node * C + col]);  // self-loop
  int e = beg;
  for (; e + 3 < end; e += 4) {
    int s0 = elist[e], s1 = elist[e + 1], s2 = elist[e + 2], s3 = elist[e + 3];
    uint4 v0 = *(const uint4*)&Hs[(long long)s0 * C + col];
    uint4 v1 = *(const uint4*)&Hs[(long long)s1 * C + col];
    uint4 v2 = *(const uint4*)&Hs[(long long)s2 * C + col];
    uint4 v3 = *(const uint4*)&Hs[(long long)s3 * C + col];
    acc8(a0, v0); acc8(a1, v1); acc8(a0, v2); acc8(a1, v3);
  }
  for (; e < end; ++e) {
    uint4 v0 = *(const uint4*)&Hs[(long long)elist[e] * C + col];
    acc8(a0, v0);
  }
  const float dv = dinv[node];
  float o[8];
#pragma unroll
  for (int i = 0; i < 8; ++i) {
    o[i] = (a0[i] + a1[i]) * dv + bias[col + i];
    if (RELU) o[i] = fmaxf(o[i], 0.f);
  }
  *(float4*)&OUT[(long long)node * C + col] = make_float4(o[0], o[1], o[2], o[3]);
  *(float4*)&OUT[(long long)node * C + col + 4] = make_float4(o[4], o[5], o[6], o[7]);
}

extern "C" void kernel_launch(void* const* d_in, const int* in_sizes, int n_in,
                              void* d_out, int out_size, void* d_ws, size_t ws_size,
                              hipStream_t stream) {
  const float* x  = (const float*)d_in[0];
  const void*  ei = d_in[1];
  const float* W1 = (const float*)d_in[2];
  const float* b1 = (const float*)d_in[3];
  const float* W2 = (const float*)d_in[4];
  const float* b2 = (const float*)d_in[5];
  float* out = (float*)d_out;
  const int N = in_sizes[0] / 512;  // 50000
  const int E = in_sizes[1] / 2;    // 1600000
  const int NB = (N + BSIZE - 1) >> BSHIFT;       // 98
  const int nchunks = (E + CHUNK - 1) / CHUNK;    // 391

  char* ws = (char*)d_ws;
  size_t off = 0;
  auto take = [&](size_t bytes) {
    void* p = ws + off;
    off = (off + bytes + 255) & ~(size_t)255;
    return p;
  };
  float* dinv   = (float*)take((size_t)N * 4);
  int*   rowptr = (int*)take((size_t)(N + 1) * 4);
  int*   ccur   = (int*)take((size_t)NBMAX * 4);
  unsigned short* elist = (unsigned short*)take((size_t)E * 2);
  unsigned short* Wt1h = (unsigned short*)take((size_t)512 * 128 * 2);
  unsigned short* Wt1l = (unsigned short*)take((size_t)512 * 128 * 2);
  unsigned short* Wt2h = (unsigned short*)take((size_t)128 * 64 * 2);
  unsigned short* Wt2l = (unsigned short*)take((size_t)128 * 64 * 2);
  unsigned short* Hs = (unsigned short*)take((size_t)N * 128 * 2);  // bf16
  float* h2     = (float*)take((size_t)N * 128 * 4);
  unsigned short* Hs2 = Hs;           // alias: Hs dead after k_gather<128>
  unsigned* pairs = (unsigned*)h2;    // alias: pairs dead before h2 written
                                      // (needs NB*CAP*4 = 12.8 MB <= 25.6 MB)

  const int B = 256;
  constexpr int WJOBS = (512 * 128 + 128 * 64) / 256;  // 288
  // CSR build + weight prep (2 kernels + 1 memset)
  hipMemsetAsync(ccur, 0, (size_t)NBMAX * 4, stream);
  k_binA<<<nchunks + WJOBS, B, 0, stream>>>(ei, ccur, pairs,
                                            W1, Wt1h, Wt1l, W2, Wt2h, Wt2l,
                                            E, NB, nchunks);
  k_binB<<<NB, B, 0, stream>>>(pairs, ccur, rowptr, dinv, elist, N, NB, E);
  // layer 1: BM=64, BN=128 -> 782 blocks (~3/CU)
  k_gemm_mfma<512, 128, 32, 2, 2><<<(N + 63) / 64, B, 0, stream>>>(
      x, Wt1h, Wt1l, dinv, Hs, N);
  k_gather<128, true><<<(N + 15) / 16, B, 0, stream>>>(rowptr, elist, dinv, Hs, b1, h2, N);
  // layer 2: BM=128, BN=64 -> 391 blocks
  k_gemm_mfma<128, 64, 32, 4, 1><<<(N + 127) / 128, B, 0, stream>>>(
      h2, Wt2h, Wt2l, dinv, Hs2, N);
  k_gather<64, false><<<(N + 31) / 32, B, 0, stream>>>(rowptr, elist, dinv, Hs2, b2, out, N);
}